// Round 4
// baseline (1062.968 us; speedup 1.0000x reference)
//
#include <hip/hip_runtime.h>
#include <stdint.h>

// FlowNet correlation, kernel_size=1, max_disp=4.
// out[b, (dy+4)*9+(dx+4), y, x] = (1/C) * sum_c in1[b,c,y,x]*in2[b,c,y+dy,x+dx]
//
// Block = 8x64 output tile, 576 thr = 9 waves, wave w owns dy=w (uniform).
// Thread = (dy, yi, xt): 8 consecutive x, acc[9 dx][8 x] in regs.
// C in CK=8 chunks staged via global_load_lds into STATICALLY-NAMED double
// buffers (s1A/s2A vs s1B/s2B). R3 used one array with runtime bs index ->
// compiler couldn't prove DMA dest != compute-read buffer -> serialized.
// Named objects make disjointness provable; T3 2-phase schedule:
//   STAGE(next->B); COMPUTE(A); vmcnt(0); s_barrier; (swap)
// s2 OOB slots are exec-masked at DMA time and pre-zeroed once.

#define BB 8
#define CC 96
#define HH 160
#define WW 320
#define TY 8
#define TX 64
#define CK 8
#define NCH (CC / CK)        // 12
#define S1W 68               // 17 16B-slots/row, odd -> bank spread
#define S2W 76               // 19 16B-slots/row, odd -> bank spread
#define NT 576
#define HWSZ (HH * WW)

#define S1_F4 (CK * TY * S1W / 4)        // 1088 float4 slots
#define S2_F4 (CK * (TY + 8) * S2W / 4)  // 2432
#define N1 (S1_F4 / 64)                  // 17 1KB wave-instructions
#define N2 (S2_F4 / 64)                  // 38
#define NINST (N1 + N2)                  // 55
#define NSTG 7                           // ceil(55/9) per wave

typedef const __attribute__((address_space(1))) void* gptr_t;
typedef __attribute__((address_space(3))) void* lptr_t;

__global__ __launch_bounds__(NT, 1)
void corr_kernel(const float* __restrict__ in1,
                 const float* __restrict__ in2,
                 float* __restrict__ out) {
    const int x0 = blockIdx.x * TX;
    const int y0 = blockIdx.y * TY;
    const int b  = blockIdx.z;

    const int tid  = threadIdx.x;
    const int wid  = tid >> 6;       // 0..8 = dy, uniform per wave
    const int lane = tid & 63;
    const int dy   = wid;
    const int yi   = lane >> 3;      // 0..7 output row in tile
    const int xt   = lane & 7;       // 0..7 -> 8-pixel x sub-block

    __shared__ __align__(16) float s1A[CK][TY][S1W];
    __shared__ __align__(16) float s2A[CK][TY + 8][S2W];
    __shared__ __align__(16) float s1B[CK][TY][S1W];
    __shared__ __align__(16) float s2B[CK][TY + 8][S2W];

    // ---- per-thread staging descriptors (once) ----
    // wave-instruction j = wid + 9*t stages 1KB: linear f4-slot j*64+lane
    // -> padded-layout (k,row,xoff); pad/OOB lanes exec-masked off.
    int goff[NSTG];
    unsigned vmask = 0;
#pragma unroll
    for (int t = 0; t < NSTG; ++t) {
        goff[t] = 0;
        const int j = wid + 9 * t;
        if (j < N1) {                                    // in1 tile
            const int f4 = j * 64 + lane;
            const int kr = f4 / 17, c4 = f4 % 17;
            const int k = kr >> 3, r = kr & 7;
            if (c4 < 16) {
                vmask |= 1u << t;
                goff[t] = (k * HH + y0 + r) * WW + x0 + 4 * c4;
            }
        } else if (j < NINST) {                          // in2 halo tile
            const int f4 = (j - N1) * 64 + lane;
            const int kr = f4 / 19, c4 = f4 % 19;
            const int k = kr >> 4, r = kr & 15;
            const int yy = y0 + r - 4;
            const int xs = x0 - 4 + 4 * c4;
            if (c4 < 18 && (unsigned)yy < (unsigned)HH &&
                (unsigned)xs <= (unsigned)(WW - 4)) {
                vmask |= 1u << t;
                goff[t] = (k * HH + yy) * WW + xs;
            }
        }
    }

#define STAGE(S1, S2, c0)                                                     \
    {                                                                         \
        const int cbase_ = (b * CC + (c0)) * HWSZ;                            \
        _Pragma("unroll")                                                     \
        for (int t = 0; t < NSTG; ++t) {                                      \
            const int j_ = wid + 9 * t;                                       \
            if (j_ < N1) {                                                    \
                if (vmask & (1u << t))                                        \
                    __builtin_amdgcn_global_load_lds(                         \
                        (gptr_t)(in1 + cbase_ + goff[t]),                     \
                        (lptr_t)((char*)(&S1[0][0][0]) + (size_t)j_ * 1024),  \
                        16, 0, 0);                                            \
            } else if (j_ < NINST) {                                          \
                if (vmask & (1u << t))                                        \
                    __builtin_amdgcn_global_load_lds(                         \
                        (gptr_t)(in2 + cbase_ + goff[t]),                     \
                        (lptr_t)((char*)(&S2[0][0][0]) +                      \
                                 (size_t)(j_ - N1) * 1024),                   \
                        16, 0, 0);                                            \
            }                                                                 \
        }                                                                     \
    }

#define COMPUTE(S1, S2)                                                       \
    {                                                                         \
        _Pragma("unroll")                                                     \
        for (int k = 0; k < CK; ++k) {                                        \
            float a[8], v[16];                                                \
            *(float4*)&a[0] = *(const float4*)&S1[k][yi][8 * xt];             \
            *(float4*)&a[4] = *(const float4*)&S1[k][yi][8 * xt + 4];         \
            _Pragma("unroll")                                                 \
            for (int q = 0; q < 4; ++q)                                       \
                *(float4*)&v[4 * q] =                                         \
                    *(const float4*)&S2[k][yi + dy][8 * xt + 4 * q];          \
            _Pragma("unroll")                                                 \
            for (int dxi = 0; dxi < 9; ++dxi)                                 \
                _Pragma("unroll")                                             \
                for (int xi = 0; xi < 8; ++xi)                                \
                    acc[dxi][xi] = fmaf(a[xi], v[xi + dxi], acc[dxi][xi]);    \
        }                                                                     \
    }

    // ---- pre-zero s2 buffers: OOB slots stay zero across all chunks ----
    {
        const float4 z4 = make_float4(0.f, 0.f, 0.f, 0.f);
        float4* za = (float4*)&s2A[0][0][0];
        float4* zb = (float4*)&s2B[0][0][0];
        for (int i = tid; i < S2_F4; i += NT) { za[i] = z4; zb[i] = z4; }
    }
    __syncthreads();                 // zeros visible before any DMA lands

    float acc[9][8];
#pragma unroll
    for (int i = 0; i < 9; ++i)
#pragma unroll
        for (int j = 0; j < 8; ++j) acc[i][j] = 0.0f;

    // ---- prologue ----
    STAGE(s1A, s2A, 0);
    asm volatile("s_waitcnt vmcnt(0)" ::: "memory");
    __builtin_amdgcn_s_barrier();

    // ---- 2-phase main loop, compile-time buffer alternation ----
    for (int ch = 0; ch < NCH; ch += 2) {
        STAGE(s1B, s2B, (ch + 1) * CK);      // DMA -> B in flight
        COMPUTE(s1A, s2A);                   // reads A (provably disjoint)
        asm volatile("s_waitcnt vmcnt(0)" ::: "memory");
        __builtin_amdgcn_s_barrier();        // B landed; all done reading A

        if (ch + 2 < NCH) STAGE(s1A, s2A, (ch + 2) * CK);
        COMPUTE(s1B, s2B);
        asm volatile("s_waitcnt vmcnt(0)" ::: "memory");
        __builtin_amdgcn_s_barrier();
    }

    // ---- epilogue: scale by 1/C, vectorized store ----
    const float scale = 1.0f / (float)CC;
#pragma unroll
    for (int dxi = 0; dxi < 9; ++dxi) {
        float4 o0 = make_float4(acc[dxi][0] * scale, acc[dxi][1] * scale,
                                acc[dxi][2] * scale, acc[dxi][3] * scale);
        float4 o1 = make_float4(acc[dxi][4] * scale, acc[dxi][5] * scale,
                                acc[dxi][6] * scale, acc[dxi][7] * scale);
        float* dst = out +
            (((b * 81 + dy * 9 + dxi) * HH + y0 + yi) * WW + x0 + 8 * xt);
        *(float4*)dst       = o0;
        *(float4*)(dst + 4) = o1;
    }
#undef STAGE
#undef COMPUTE
}

extern "C" void kernel_launch(void* const* d_in, const int* in_sizes, int n_in,
                              void* d_out, int out_size, void* d_ws, size_t ws_size,
                              hipStream_t stream) {
    const float* in1 = (const float*)d_in[0];
    const float* in2 = (const float*)d_in[1];
    float* out = (float*)d_out;
    dim3 grid(WW / TX, HH / TY, BB);  // 5 x 20 x 8 = 800 blocks
    corr_kernel<<<grid, NT, 0, stream>>>(in1, in2, out);
}

// Round 5
// 305.246 us; speedup vs baseline: 3.4823x; 3.4823x over previous
//
#include <hip/hip_runtime.h>

// FlowNet correlation, kernel_size=1, max_disp=4.
// out[b, (dy+4)*9+(dx+4), y, x] = (1/C) * sum_c in1[b,c,y,x]*in2[b,c,y+dy,x+dx]
//
// R5 restructure: thread owns 4 x-pixels (acc[9][4]=36 regs, was 72 -> the
// 9-wave block is no longer register-capped; R2-R4's phantom GB of HBM
// traffic was unified-file spill at the ~170-reg/wave budget).
// Tile 8x32, 9 waves (wave = dy), 576 thr. in1 NOT staged (thread-private
// a[4] from global; 9x wave reuse served by L1). in2 staged in ONE 22 KB
// LDS buffer -> 2-3 blocks/CU; plain stage/sync/compute/sync, latency
// hidden by cross-block TLP (m114), zero compiler-hostile constructs.
// LDS row stride 44 floats (=12 mod 32 banks) spreads row starts across
// banks for conflict-free b128 reads. OOB halo slots zeroed once, never
// rewritten (whole-slot OOB by construction: x0%32==0, halo offset -4).

#define BB 8
#define CC 96
#define HH 160
#define WW 320
#define TY 8
#define TX 32
#define CK 8
#define NCH (CC / CK)            // 12
#define HR (TY + 8)              // 16 halo rows
#define SW 44                    // LDS row stride floats: 11 f4 slots (10 data + 1 pad)
#define NT 576
#define HW (HH * WW)
#define NSLOT (CK * HR * (SW / 4))   // 1408 f4 slots
#define NSTG 3                       // ceil(1408/576)

__global__ __launch_bounds__(NT, 4)
void corr_kernel(const float* __restrict__ in1,
                 const float* __restrict__ in2,
                 float* __restrict__ out) {
    const int x0 = blockIdx.x * TX;
    const int y0 = blockIdx.y * TY;
    const int b  = blockIdx.z;

    const int tid  = threadIdx.x;
    const int dy   = tid >> 6;       // 0..8 = dy+4, uniform per wave
    const int lane = tid & 63;
    const int yi   = lane >> 3;      // 0..7 output row in tile
    const int xt   = lane & 7;       // 0..7 -> 4-pixel x sub-block

    __shared__ __align__(16) float s2[CK][HR][SW];

    // ---- staging descriptors (once): slot i = tid + t*NT ----
    int goff[NSTG];
    float4* lsl[NSTG];
    bool ok[NSTG];
#pragma unroll
    for (int t = 0; t < NSTG; ++t) {
        const int i = tid + t * NT;
        ok[t] = false; goff[t] = 0; lsl[t] = (float4*)&s2[0][0][0];
        if (i < NSLOT) {
            const int k = i / (HR * 11), rem = i % (HR * 11);
            const int r = rem / 11, c4 = rem % 11;
            lsl[t] = (float4*)&s2[k][r][4 * c4];
            const int yy = y0 + r - 4;
            const int xs = x0 - 4 + 4 * c4;
            if (c4 < 10 && (unsigned)yy < (unsigned)HH &&
                (unsigned)xs <= (unsigned)(WW - 4)) {
                ok[t] = true;
                goff[t] = (k * HH + yy) * WW + xs;
            }
        }
    }

    // ---- zero LDS once: OOB/pad slots stay zero across all chunks ----
    {
        const float4 z = make_float4(0.f, 0.f, 0.f, 0.f);
        float4* p = (float4*)&s2[0][0][0];
        for (int i = tid; i < NSLOT; i += NT) p[i] = z;
    }

    float acc[9][4];
#pragma unroll
    for (int i = 0; i < 9; ++i)
#pragma unroll
        for (int j = 0; j < 4; ++j) acc[i][j] = 0.0f;

    const float* in1p = in1 + ((size_t)(b * CC) * HH + y0 + yi) * WW + x0 + 4 * xt;

    for (int ch = 0; ch < NCH; ++ch) {
        const int cb = (b * CC + ch * CK) * HW;
        __syncthreads();                     // all readers of prev chunk done
#pragma unroll
        for (int t = 0; t < NSTG; ++t)
            if (ok[t]) *lsl[t] = *(const float4*)(in2 + cb + goff[t]);
        __syncthreads();                     // chunk visible

#pragma unroll
        for (int k = 0; k < CK; ++k) {
            float a[4];
            *(float4*)a = *(const float4*)(in1p + (size_t)(ch * CK + k) * HW);
            float v[12];
#pragma unroll
            for (int q = 0; q < 3; ++q)
                *(float4*)&v[4 * q] = *(const float4*)&s2[k][yi + dy][4 * xt + 4 * q];
#pragma unroll
            for (int dxi = 0; dxi < 9; ++dxi)
#pragma unroll
                for (int xi = 0; xi < 4; ++xi)
                    acc[dxi][xi] = fmaf(a[xi], v[xi + dxi], acc[dxi][xi]);
        }
    }

    // ---- epilogue: scale by 1/C, one float4 store per dx ----
    const float scale = 1.0f / (float)CC;
#pragma unroll
    for (int dxi = 0; dxi < 9; ++dxi) {
        float4 o = make_float4(acc[dxi][0] * scale, acc[dxi][1] * scale,
                               acc[dxi][2] * scale, acc[dxi][3] * scale);
        float* dst = out +
            (((size_t)(b * 81 + dy * 9 + dxi) * HH + y0 + yi) * WW + x0 + 4 * xt);
        *(float4*)dst = o;
    }
}

extern "C" void kernel_launch(void* const* d_in, const int* in_sizes, int n_in,
                              void* d_out, int out_size, void* d_ws, size_t ws_size,
                              hipStream_t stream) {
    const float* in1 = (const float*)d_in[0];
    const float* in2 = (const float*)d_in[1];
    float* out = (float*)d_out;
    dim3 grid(WW / TX, HH / TY, BB);  // 10 x 20 x 8 = 1600 blocks
    corr_kernel<<<grid, NT, 0, stream>>>(in1, in2, out);
}